// Round 9
// baseline (518.382 us; speedup 1.0000x reference)
//
#include <hip/hip_runtime.h>
#include <hip/hip_bf16.h>
#include <cstdint>
#include <cstddef>

#define D_MODEL 1024
#define N_EXP   8
#define HID     4096
#define T_TOK   4096          // B*S
#define NPAIR   (T_TOK * 2)   // top-2
#define WSL256  40            // max 256-row m-tiles: 8192/256 + 7 = 39

// ---------------- workspace layout (bytes) ----------------
#define WS_COUNTS   0
#define WS_CURSOR   32
#define WS_OFFSETS  64
#define WS_TOKE     128                       // tok_e[T][2] int
#define WS_TOKG     32896                     // tok_g[T][2] float
#define WS_LTOK     65664                     // list_tok[NPAIR] int
#define WS_LGATE    98432                     // list_gate[NPAIR] float
#define WS_XB       131328                    // xb[T][1024] bf16        (8 MB)
#define WS_WB       (WS_XB + 8388608)         // Wt shared buf bf16      (64 MB)
#define WS_H        (WS_WB + 67108864)        // H[NPAIR][4096] bf16     (64 MB)

typedef __attribute__((ext_vector_type(8))) short bf16x8;
typedef __attribute__((ext_vector_type(4))) float f32x4;
typedef __attribute__((ext_vector_type(8))) unsigned short u16x8;
typedef unsigned short u16;

__device__ __forceinline__ u16 f2bf(float f) {
    unsigned u = __float_as_uint(f);
    u += 0x7FFFu + ((u >> 16) & 1u);          // RNE
    return (u16)(u >> 16);
}

__device__ __forceinline__ void glds16(const void* g, void* l) {
    __builtin_amdgcn_global_load_lds(
        (const __attribute__((address_space(1))) void*)g,
        (__attribute__((address_space(3))) void*)l, 16, 0, 0);
}

// Swizzled-stage chunk map (validated r3/r6: conflicts 0, bit-exact output).
// LDS tile: rows x 32 bf16, 2 rows per 128B line (8 x 16B chunks), chunk slot
// XOR-swizzled by (line&7). Read side uses matching XOR. Works for any row
// count (lines = rows/2).
__device__ __forceinline__ void chunk_map(int c, int& row, int& kc) {
    const int line = c >> 3, c8 = c & 7, u = c8 ^ (line & 7);
    row = line * 2 + (u >> 2);
    kc  = (u & 3) * 8;                        // ushort offset in 32-wide K window
}

// compact worklist: slot w -> (expert, 256-row m_tile). uniform per block.
__device__ __forceinline__ bool work_map256(const int* counts, int w,
                                            int& e, int& m_t) {
    int tot = 0; e = -1; m_t = 0;
    #pragma unroll
    for (int i = 0; i < N_EXP; ++i) {
        const int tl = (counts[i] + 255) >> 8;
        if (e < 0 && w < tot + tl) { e = i; m_t = w - tot; }
        tot += tl;
    }
    return e >= 0;
}

// ---------------------------------------------------------------------------
// Router (validated) + fused x -> bf16 emission (validated r4)
// ---------------------------------------------------------------------------
__global__ __launch_bounds__(256) void k_router(
    const float* __restrict__ x, const float* __restrict__ noise,
    const float* __restrict__ Wr, const float* __restrict__ br,
    const float* __restrict__ Wn, const float* __restrict__ bn,
    int* __restrict__ counts, int* __restrict__ tok_e, float* __restrict__ tok_g,
    u16* __restrict__ xb)
{
    const int t   = blockIdx.x;
    const int tid = threadIdx.x;
    const int e   = tid & 7;
    const int g   = tid >> 3;
    const float* xr = x + (size_t)t * D_MODEL;

    {
        const float4 v4 = *(const float4*)(xr + tid * 4);
        ushort4 o;
        o.x = f2bf(v4.x); o.y = f2bf(v4.y); o.z = f2bf(v4.z); o.w = f2bf(v4.w);
        *(ushort4*)(xb + (size_t)t * D_MODEL + tid * 4) = o;
    }

    float ar = 0.f, an = 0.f;
    const int ibase = g * 32;
    #pragma unroll 8
    for (int j = 0; j < 32; ++j) {
        const int i = ibase + j;
        const float xv = xr[i];
        ar = fmaf(xv, Wr[i * 8 + e], ar);
        an = fmaf(xv, Wn[i * 8 + e], an);
    }

    __shared__ float sR[256], sN[256];
    sR[tid] = ar; sN[tid] = an;
    __syncthreads();
    for (int off = 128; off >= 8; off >>= 1) {
        if (tid < off) { sR[tid] += sR[tid + off]; sN[tid] += sN[tid + off]; }
        __syncthreads();
    }

    __shared__ float lg[8];
    if (tid < 8) {
        const float z  = sN[tid] + bn[tid];
        const float sp = fmaxf(z, 0.f) + log1pf(expf(-fabsf(z)));
        lg[tid] = sR[tid] + br[tid] + sp * noise[t * 8 + tid];
    }
    __syncthreads();

    if (tid == 0) {
        float v0 = -INFINITY, v1 = -INFINITY;
        int   i0 = 0,         i1 = 0;
        #pragma unroll
        for (int ee = 0; ee < 8; ++ee) {
            const float v = lg[ee];
            if (v > v0)      { v1 = v0; i1 = i0; v0 = v; i0 = ee; }
            else if (v > v1) { v1 = v;  i1 = ee; }
        }
        const float ew  = expf(v1 - v0);
        const float inv = 1.f / (1.f + ew);
        tok_e[t * 2 + 0] = i0;
        tok_e[t * 2 + 1] = i1;
        tok_g[t * 2 + 0] = inv;
        tok_g[t * 2 + 1] = ew * inv;
        atomicAdd(&counts[i0], 1);
        atomicAdd(&counts[i1], 1);
    }
}

__global__ void k_prefix(const int* __restrict__ counts, int* __restrict__ offsets)
{
    if (threadIdx.x == 0 && blockIdx.x == 0) {
        int acc = 0;
        #pragma unroll
        for (int e = 0; e < N_EXP; ++e) { offsets[e] = acc; acc += counts[e]; }
    }
}

__global__ __launch_bounds__(256) void k_scatter(
    const int* __restrict__ tok_e, const float* __restrict__ tok_g,
    const int* __restrict__ offsets, int* __restrict__ cursor,
    int* __restrict__ list_tok, float* __restrict__ list_gate)
{
    const int gid = blockIdx.x * 256 + threadIdx.x;
    if (gid >= NPAIR) return;
    const int e = tok_e[gid];
    const int p = atomicAdd(&cursor[e], 1);
    const int slot = offsets[e] + p;
    list_tok[slot]  = gid >> 1;
    list_gate[slot] = tok_g[gid];
}

// ---------------------------------------------------------------------------
// Per-expert transpose+convert: f32 [E][R][C] -> bf16 [E][C][R]  (r5 version)
// ---------------------------------------------------------------------------
__global__ __launch_bounds__(256) void k_cvtT(
    const float* __restrict__ in, u16* __restrict__ outp, int R, int C)
{
    const size_t esz = (size_t)R * C;
    const float* ine = in + (size_t)blockIdx.z * esz;
    u16* oute = outp + (size_t)blockIdx.z * esz;
    const int c0 = blockIdx.x * 32, r0 = blockIdx.y * 64;

    __shared__ u16 s[64 * 33];
    const int tid = threadIdx.x;
    const int lr = tid >> 3, lc = (tid & 7) * 4;
    #pragma unroll
    for (int p = 0; p < 2; ++p) {
        const int row = lr + p * 32;
        const float4 v = *(const float4*)(ine + (size_t)(r0 + row) * C + c0 + lc);
        s[row * 33 + lc + 0] = f2bf(v.x);
        s[row * 33 + lc + 1] = f2bf(v.y);
        s[row * 33 + lc + 2] = f2bf(v.z);
        s[row * 33 + lc + 3] = f2bf(v.w);
    }
    __syncthreads();
    const int oc = tid >> 3, rr = (tid & 7) * 8;
    u16x8 o;
    #pragma unroll
    for (int i = 0; i < 8; ++i) o[i] = s[(rr + i) * 33 + oc];
    *(u16x8*)(oute + (size_t)(c0 + oc) * R + r0 + rr) = o;
}

// ---------------------------------------------------------------------------
// Grouped deep-pipeline GEMM1: H = relu(Xg @ W1t^T + b1).
// 256x256 tile, BK=32, 512 thr (8 waves 2Mx4N, wave 128x64, acc[8][4]).
// 4 LDS buffers (132 KB, 1 block/CU), prefetch distance 2, ONE barrier/K-step,
// counted vmcnt(4) (4 glds16/thread/K-tile), setprio around MFMA clusters.
// grid = 16 n * WSL256; n_t&7 = XCD.
// ---------------------------------------------------------------------------
__global__ __launch_bounds__(512, 2) void k_ffn1(
    const u16* __restrict__ xb,     // [T][1024]
    const u16* __restrict__ W1t,    // [E][4096][1024]
    const float* __restrict__ b1,
    const int* __restrict__ counts, const int* __restrict__ offsets,
    const int* __restrict__ list_tok,
    u16* __restrict__ H)            // [NPAIR][4096]
{
    const int bid = blockIdx.x;
    const int n_t = (bid & 7) | (((bid >> 3) & 1) << 3);   // 0..15, n_t&7 = XCD
    const int wsl = bid >> 4;

    int e, m_t;
    if (!work_map256(counts, wsl, e, m_t)) return;
    const int cnt  = counts[e];
    const int base = offsets[e];
    const int m0   = m_t * 256;
    const int n0   = n_t * 256;
    const u16* __restrict__ Be = W1t + (size_t)e * (HID * D_MODEL);

    __shared__ __align__(16) u16 SA[4 * 8192];  // 4 buf x (256 x 32) = 64 KB
    __shared__ __align__(16) u16 SB[4 * 8192];  // 64 KB
    __shared__ int stok[256];

    const int tid = threadIdx.x;
    if (tid < 256) stok[tid] = list_tok[base + min(m0 + tid, cnt - 1)];
    __syncthreads();

    int ar0, ak0, ar1, ak1;
    chunk_map(tid, ar0, ak0);          // rows   0..127
    chunk_map(tid + 512, ar1, ak1);    // rows 128..255
    const u16* Asrc0 = xb + (size_t)stok[ar0] * D_MODEL + ak0;
    const u16* Asrc1 = xb + (size_t)stok[ar1] * D_MODEL + ak1;
    const u16* Bsrc0 = Be + (size_t)(n0 + ar0) * D_MODEL + ak0;
    const u16* Bsrc1 = Be + (size_t)(n0 + ar1) * D_MODEL + ak1;

    const int lane = tid & 63, lr = lane & 15, hk = lane >> 4;
    const int w = tid >> 6, wm = w >> 2, wn = w & 3;        // 2M x 4N
    const int colb  = ((((lr & 1) << 2) + hk) ^ (lr >> 1)) << 4;
    const int baseA = ((wm * 64 + (lr >> 1)) << 7) + colb;  // wave rows wm*128
    const int baseB = ((wn * 32 + (lr >> 1)) << 7) + colb;  // wave cols wn*64

    float bias[4];
    #pragma unroll
    for (int j = 0; j < 4; ++j) bias[j] = b1[(size_t)e * HID + n0 + wn * 64 + j * 16 + lr];

    f32x4 acc[8][4] = {};

    auto STAGE = [&](int s, int t) {
        const int kt = t * 32;
        char* Ab = (char*)SA + s * 16384;
        char* Bb = (char*)SB + s * 16384;
        glds16(Asrc0 + kt, Ab + tid * 16);
        glds16(Asrc1 + kt, Ab + (tid + 512) * 16);
        glds16(Bsrc0 + kt, Bb + tid * 16);
        glds16(Bsrc1 + kt, Bb + (tid + 512) * 16);
    };
    auto COMPUTE = [&](int s) {
        const char* Ab = (const char*)SA + s * 16384;
        const char* Bb = (const char*)SB + s * 16384;
        bf16x8 b[4];
        #pragma unroll
        for (int j = 0; j < 4; ++j) b[j] = *(const bf16x8*)(Bb + baseB + j * 1024);
        // phase 0: A rows 0..63 of wave tile
        {
            bf16x8 a[4];
            #pragma unroll
            for (int i = 0; i < 4; ++i) a[i] = *(const bf16x8*)(Ab + baseA + i * 1024);
            __builtin_amdgcn_s_setprio(1);
            #pragma unroll
            for (int i = 0; i < 4; ++i)
                #pragma unroll
                for (int j = 0; j < 4; ++j)
                    acc[i][j] = __builtin_amdgcn_mfma_f32_16x16x32_bf16(a[i], b[j], acc[i][j], 0, 0, 0);
            __builtin_amdgcn_s_setprio(0);
        }
        // phase 1: A rows 64..127 of wave tile
        {
            bf16x8 a[4];
            #pragma unroll
            for (int i = 0; i < 4; ++i) a[i] = *(const bf16x8*)(Ab + baseA + (i + 4) * 1024);
            __builtin_amdgcn_s_setprio(1);
            #pragma unroll
            for (int i = 0; i < 4; ++i)
                #pragma unroll
                for (int j = 0; j < 4; ++j)
                    acc[i + 4][j] = __builtin_amdgcn_mfma_f32_16x16x32_bf16(a[i], b[j], acc[i + 4][j], 0, 0, 0);
            __builtin_amdgcn_s_setprio(0);
        }
    };

    const int NT = D_MODEL / 32;                // 32
    STAGE(0, 0);
    STAGE(1, 1);
    for (int t = 0; t < NT; ++t) {
        if (t < NT - 1) { asm volatile("s_waitcnt vmcnt(4)" ::: "memory"); }
        else            { asm volatile("s_waitcnt vmcnt(0)" ::: "memory"); }
        __builtin_amdgcn_s_barrier();
        __builtin_amdgcn_sched_barrier(0);
        if (t + 2 < NT) STAGE((t + 2) & 3, t + 2);
        __builtin_amdgcn_sched_barrier(0);
        COMPUTE(t & 3);
    }

    #pragma unroll
    for (int i = 0; i < 8; ++i) {
        #pragma unroll
        for (int g = 0; g < 4; ++g) {
            const int m = m0 + wm * 128 + i * 16 + hk * 4 + g;
            if (m < cnt) {
                u16* dst = H + (size_t)(base + m) * HID + n0 + wn * 64 + lr;
                #pragma unroll
                for (int j = 0; j < 4; ++j)
                    dst[j * 16] = f2bf(fmaxf(acc[i][j][g] + bias[j], 0.f));
            }
        }
    }
}

// ---------------------------------------------------------------------------
// Grouped deep-pipeline GEMM2: out += gate*(H @ W2t^T + b2).
// 256x128 tile, split-K=2 (block sums K=2048; kh==0 adds bias; 4 f32 atomics
// per out elem). 512 thr (8 waves 4Mx2N, wave 64x64, acc[4][4]). 4 LDS
// buffers (100 KB), prefetch distance 2, ONE barrier/K-step, vmcnt(3)
// (3 glds16/thread/K-tile), setprio MFMA cluster. grid = 8 n * 2 kh * WSL256.
// ---------------------------------------------------------------------------
__global__ __launch_bounds__(512, 2) void k_ffn2(
    const u16* __restrict__ Hb,     // [NPAIR][4096]
    const u16* __restrict__ W2t,    // [E][1024][4096]
    const float* __restrict__ b2,
    const int* __restrict__ counts, const int* __restrict__ offsets,
    const int* __restrict__ list_tok, const float* __restrict__ list_gate,
    float* __restrict__ out)
{
    const int bid = blockIdx.x;
    const int n_t = bid & 7;                    // XCD-exclusive W2t panel
    const int kh  = (bid >> 3) & 1;
    const int wsl = bid >> 4;

    int e, m_t;
    if (!work_map256(counts, wsl, e, m_t)) return;
    const int cnt  = counts[e];
    const int base = offsets[e];
    const int m0   = m_t * 256;
    const int n0   = n_t * 128;
    const int k0   = kh * (HID / 2);            // 0 or 2048
    const u16* __restrict__ Be = W2t + (size_t)e * (D_MODEL * HID);

    __shared__ __align__(16) u16 SA[4 * 8192];  // 4 buf x (256 x 32) = 64 KB
    __shared__ __align__(16) u16 SB[4 * 4096];  // 4 buf x (128 x 32) = 32 KB
    __shared__ int   s_tok[256];
    __shared__ float s_gate[256];

    const int tid = threadIdx.x;
    if (tid < 256) {
        const int sl = base + min(m0 + tid, cnt - 1);
        s_tok[tid]  = list_tok[sl];
        s_gate[tid] = list_gate[sl];
    }
    __syncthreads();

    int ar0, ak0, ar1, ak1;
    chunk_map(tid, ar0, ak0);          // rows   0..127 (A) / all of B
    chunk_map(tid + 512, ar1, ak1);    // rows 128..255 (A)
    const u16* Asrc0 = Hb + (size_t)(base + min(m0 + ar0, cnt - 1)) * HID + k0 + ak0;
    const u16* Asrc1 = Hb + (size_t)(base + min(m0 + ar1, cnt - 1)) * HID + k0 + ak1;
    const u16* Bsrc  = Be + (size_t)(n0 + ar0) * HID + k0 + ak0;

    const int lane = tid & 63, lr = lane & 15, hk = lane >> 4;
    const int w = tid >> 6, wm = w >> 1, wn = w & 1;        // 4M x 2N
    const int colb  = ((((lr & 1) << 2) + hk) ^ (lr >> 1)) << 4;
    const int baseA = ((wm * 32 + (lr >> 1)) << 7) + colb;  // wave rows wm*64
    const int baseB = ((wn * 32 + (lr >> 1)) << 7) + colb;  // wave cols wn*64

    float bias[4];
    #pragma unroll
    for (int j = 0; j < 4; ++j)
        bias[j] = (kh == 0) ? b2[(size_t)e * D_MODEL + n0 + wn * 64 + j * 16 + lr] : 0.f;

    f32x4 acc[4][4] = {};

    auto STAGE = [&](int s, int t) {
        const int kt = t * 32;
        char* Ab = (char*)SA + s * 16384;
        char* Bb = (char*)SB + s * 8192;
        glds16(Asrc0 + kt, Ab + tid * 16);
        glds16(Asrc1 + kt, Ab + (tid + 512) * 16);
        glds16(Bsrc  + kt, Bb + tid * 16);
    };
    auto COMPUTE = [&](int s) {
        const char* Ab = (const char*)SA + s * 16384;
        const char* Bb = (const char*)SB + s * 8192;
        bf16x8 a[4], b[4];
        #pragma unroll
        for (int i = 0; i < 4; ++i) a[i] = *(const bf16x8*)(Ab + baseA + i * 1024);
        #pragma unroll
        for (int j = 0; j < 4; ++j) b[j] = *(const bf16x8*)(Bb + baseB + j * 1024);
        __builtin_amdgcn_s_setprio(1);
        #pragma unroll
        for (int i = 0; i < 4; ++i)
            #pragma unroll
            for (int j = 0; j < 4; ++j)
                acc[i][j] = __builtin_amdgcn_mfma_f32_16x16x32_bf16(a[i], b[j], acc[i][j], 0, 0, 0);
        __builtin_amdgcn_s_setprio(0);
    };

    const int NT = (HID / 2) / 32;              // 64
    STAGE(0, 0);
    STAGE(1, 1);
    for (int t = 0; t < NT; ++t) {
        if (t < NT - 1) { asm volatile("s_waitcnt vmcnt(3)" ::: "memory"); }
        else            { asm volatile("s_waitcnt vmcnt(0)" ::: "memory"); }
        __builtin_amdgcn_s_barrier();
        __builtin_amdgcn_sched_barrier(0);
        if (t + 2 < NT) STAGE((t + 2) & 3, t + 2);
        __builtin_amdgcn_sched_barrier(0);
        COMPUTE(t & 3);
    }

    #pragma unroll
    for (int i = 0; i < 4; ++i) {
        #pragma unroll
        for (int g = 0; g < 4; ++g) {
            const int m = m0 + wm * 64 + i * 16 + hk * 4 + g;
            if (m < cnt) {
                const int   mm = m - m0;
                const int   tk = s_tok[mm];
                const float gt = s_gate[mm];
                float* dst = out + (size_t)tk * D_MODEL + n0 + wn * 64 + lr;
                #pragma unroll
                for (int j = 0; j < 4; ++j)
                    unsafeAtomicAdd(dst + j * 16, gt * (acc[i][j][g] + bias[j]));
            }
        }
    }
}

// ---------------------------------------------------------------------------
extern "C" void kernel_launch(void* const* d_in, const int* in_sizes, int n_in,
                              void* d_out, int out_size, void* d_ws, size_t ws_size,
                              hipStream_t stream)
{
    const float* x     = (const float*)d_in[0];
    const float* noise = (const float*)d_in[1];
    const float* Wr    = (const float*)d_in[2];
    const float* br    = (const float*)d_in[3];
    const float* Wn    = (const float*)d_in[4];
    const float* bn    = (const float*)d_in[5];
    const float* W1    = (const float*)d_in[6];
    const float* b1    = (const float*)d_in[7];
    const float* W2    = (const float*)d_in[8];
    const float* b2    = (const float*)d_in[9];
    float* out = (float*)d_out;

    char* ws = (char*)d_ws;
    int*   counts    = (int*)(ws + WS_COUNTS);
    int*   cursor    = (int*)(ws + WS_CURSOR);
    int*   offsets   = (int*)(ws + WS_OFFSETS);
    int*   tok_e     = (int*)(ws + WS_TOKE);
    float* tok_g     = (float*)(ws + WS_TOKG);
    int*   list_tok  = (int*)(ws + WS_LTOK);
    float* list_gate = (float*)(ws + WS_LGATE);
    u16*   xb        = (u16*)(ws + WS_XB);
    u16*   Wb        = (u16*)(ws + WS_WB);
    u16*   Hb        = (u16*)(ws + WS_H);

    hipMemsetAsync(ws, 0, 128, stream);
    hipMemsetAsync(d_out, 0, (size_t)out_size * sizeof(float), stream);

    k_cvtT<<<dim3(HID / 32, D_MODEL / 64, N_EXP), 256, 0, stream>>>(W1, Wb, D_MODEL, HID);
    k_router<<<T_TOK, 256, 0, stream>>>(x, noise, Wr, br, Wn, bn, counts, tok_e, tok_g, xb);
    k_prefix<<<1, 64, 0, stream>>>(counts, offsets);
    k_scatter<<<NPAIR / 256, 256, 0, stream>>>(tok_e, tok_g, offsets, cursor,
                                               list_tok, list_gate);

    k_ffn1<<<16 * WSL256, 512, 0, stream>>>(xb, Wb, b1, counts, offsets,
                                            list_tok, Hb);

    k_cvtT<<<dim3(D_MODEL / 32, HID / 64, N_EXP), 256, 0, stream>>>(W2, Wb, HID, D_MODEL);
    k_ffn2<<<8 * 2 * WSL256, 512, 0, stream>>>(Hb, Wb, b2, counts, offsets,
                                               list_tok, list_gate, out);
}

// Round 11
// 502.840 us; speedup vs baseline: 1.0309x; 1.0309x over previous
//
#include <hip/hip_runtime.h>
#include <hip/hip_bf16.h>
#include <cstdint>
#include <cstddef>

#define D_MODEL 1024
#define N_EXP   8
#define HID     4096
#define T_TOK   4096          // B*S
#define NPAIR   (T_TOK * 2)   // top-2
#define WSLOTS  72            // max 128-row m-tiles: 8192/128 + 7 = 71
#define WSL256  40            // max 256-row m-tiles: 8192/256 + 7 = 39

// ---------------- workspace layout (bytes) ----------------
#define WS_COUNTS   0
#define WS_CURSOR   32
#define WS_OFFSETS  64
#define WS_TOKE     128                       // tok_e[T][2] int
#define WS_TOKG     32896                     // tok_g[T][2] float
#define WS_LTOK     65664                     // list_tok[NPAIR] int
#define WS_LGATE    98432                     // list_gate[NPAIR] float
#define WS_XB       131328                    // xb[T][1024] bf16        (8 MB)
#define WS_WB       (WS_XB + 8388608)         // Wt shared buf bf16      (64 MB)
#define WS_H        (WS_WB + 67108864)        // H[NPAIR][4096] bf16     (64 MB)

typedef __attribute__((ext_vector_type(8))) short bf16x8;
typedef __attribute__((ext_vector_type(4))) float f32x4;
typedef __attribute__((ext_vector_type(8))) unsigned short u16x8;
typedef unsigned short u16;

__device__ __forceinline__ u16 f2bf(float f) {
    unsigned u = __float_as_uint(f);
    u += 0x7FFFu + ((u >> 16) & 1u);          // RNE
    return (u16)(u >> 16);
}

__device__ __forceinline__ void glds16(const void* g, void* l) {
    __builtin_amdgcn_global_load_lds(
        (const __attribute__((address_space(1))) void*)g,
        (__attribute__((address_space(3))) void*)l, 16, 0, 0);
}

// ---- BK=32 swizzle (validated r3/r6: conflicts 0, bit-exact) -------------
// LDS tile rows x 32 bf16, 2 rows per 128B line, chunk slot ^= (line&7).
__device__ __forceinline__ void chunk_map(int c, int& row, int& kc) {
    const int line = c >> 3, c8 = c & 7, u = c8 ^ (line & 7);
    row = line * 2 + (u >> 2);
    kc  = (u & 3) * 8;                        // u16 offset in 32-wide K window
}

// ---- BK=64 swizzle: one row per 128B line, slot = u ^ (row&7) ------------
// stage: LDS 16B-slot s -> row = s>>3, global k-chunk u = (s&7)^(row&7).
// read:  byte = row*128 + ((v ^ (row&7))*16), v = ksub*4 + hk.
// Fragment read: 16 lanes (rows r..r+15, fixed v) hit 8 slots x2 = 2-way (free).

// compact worklist (128-row tiles): slot w -> (expert, m_tile).
__device__ __forceinline__ bool work_map(const int* counts, int w,
                                         int& e, int& m_t) {
    int tot = 0; e = -1; m_t = 0;
    #pragma unroll
    for (int i = 0; i < N_EXP; ++i) {
        const int tl = (counts[i] + 127) >> 7;
        if (e < 0 && w < tot + tl) { e = i; m_t = w - tot; }
        tot += tl;
    }
    return e >= 0;
}
// compact worklist (256-row tiles)
__device__ __forceinline__ bool work_map256(const int* counts, int w,
                                            int& e, int& m_t) {
    int tot = 0; e = -1; m_t = 0;
    #pragma unroll
    for (int i = 0; i < N_EXP; ++i) {
        const int tl = (counts[i] + 255) >> 8;
        if (e < 0 && w < tot + tl) { e = i; m_t = w - tot; }
        tot += tl;
    }
    return e >= 0;
}

// ---------------------------------------------------------------------------
// Router (validated) + fused x -> bf16 emission (validated r4)
// ---------------------------------------------------------------------------
__global__ __launch_bounds__(256) void k_router(
    const float* __restrict__ x, const float* __restrict__ noise,
    const float* __restrict__ Wr, const float* __restrict__ br,
    const float* __restrict__ Wn, const float* __restrict__ bn,
    int* __restrict__ counts, int* __restrict__ tok_e, float* __restrict__ tok_g,
    u16* __restrict__ xb)
{
    const int t   = blockIdx.x;
    const int tid = threadIdx.x;
    const int e   = tid & 7;
    const int g   = tid >> 3;
    const float* xr = x + (size_t)t * D_MODEL;

    {
        const float4 v4 = *(const float4*)(xr + tid * 4);
        ushort4 o;
        o.x = f2bf(v4.x); o.y = f2bf(v4.y); o.z = f2bf(v4.z); o.w = f2bf(v4.w);
        *(ushort4*)(xb + (size_t)t * D_MODEL + tid * 4) = o;
    }

    float ar = 0.f, an = 0.f;
    const int ibase = g * 32;
    #pragma unroll 8
    for (int j = 0; j < 32; ++j) {
        const int i = ibase + j;
        const float xv = xr[i];
        ar = fmaf(xv, Wr[i * 8 + e], ar);
        an = fmaf(xv, Wn[i * 8 + e], an);
    }

    __shared__ float sR[256], sN[256];
    sR[tid] = ar; sN[tid] = an;
    __syncthreads();
    for (int off = 128; off >= 8; off >>= 1) {
        if (tid < off) { sR[tid] += sR[tid + off]; sN[tid] += sN[tid + off]; }
        __syncthreads();
    }

    __shared__ float lg[8];
    if (tid < 8) {
        const float z  = sN[tid] + bn[tid];
        const float sp = fmaxf(z, 0.f) + log1pf(expf(-fabsf(z)));
        lg[tid] = sR[tid] + br[tid] + sp * noise[t * 8 + tid];
    }
    __syncthreads();

    if (tid == 0) {
        float v0 = -INFINITY, v1 = -INFINITY;
        int   i0 = 0,         i1 = 0;
        #pragma unroll
        for (int ee = 0; ee < 8; ++ee) {
            const float v = lg[ee];
            if (v > v0)      { v1 = v0; i1 = i0; v0 = v; i0 = ee; }
            else if (v > v1) { v1 = v;  i1 = ee; }
        }
        const float ew  = expf(v1 - v0);
        const float inv = 1.f / (1.f + ew);
        tok_e[t * 2 + 0] = i0;
        tok_e[t * 2 + 1] = i1;
        tok_g[t * 2 + 0] = inv;
        tok_g[t * 2 + 1] = ew * inv;
        atomicAdd(&counts[i0], 1);
        atomicAdd(&counts[i1], 1);
    }
}

__global__ void k_prefix(const int* __restrict__ counts, int* __restrict__ offsets)
{
    if (threadIdx.x == 0 && blockIdx.x == 0) {
        int acc = 0;
        #pragma unroll
        for (int e = 0; e < N_EXP; ++e) { offsets[e] = acc; acc += counts[e]; }
    }
}

__global__ __launch_bounds__(256) void k_scatter(
    const int* __restrict__ tok_e, const float* __restrict__ tok_g,
    const int* __restrict__ offsets, int* __restrict__ cursor,
    int* __restrict__ list_tok, float* __restrict__ list_gate)
{
    const int gid = blockIdx.x * 256 + threadIdx.x;
    if (gid >= NPAIR) return;
    const int e = tok_e[gid];
    const int p = atomicAdd(&cursor[e], 1);
    const int slot = offsets[e] + p;
    list_tok[slot]  = gid >> 1;
    list_gate[slot] = tok_g[gid];
}

// ---------------------------------------------------------------------------
// Per-expert transpose+convert: f32 [E][R][C] -> bf16 [E][C][R]  (r5 version)
// ---------------------------------------------------------------------------
__global__ __launch_bounds__(256) void k_cvtT(
    const float* __restrict__ in, u16* __restrict__ outp, int R, int C)
{
    const size_t esz = (size_t)R * C;
    const float* ine = in + (size_t)blockIdx.z * esz;
    u16* oute = outp + (size_t)blockIdx.z * esz;
    const int c0 = blockIdx.x * 32, r0 = blockIdx.y * 64;

    __shared__ u16 s[64 * 33];
    const int tid = threadIdx.x;
    const int lr = tid >> 3, lc = (tid & 7) * 4;
    #pragma unroll
    for (int p = 0; p < 2; ++p) {
        const int row = lr + p * 32;
        const float4 v = *(const float4*)(ine + (size_t)(r0 + row) * C + c0 + lc);
        s[row * 33 + lc + 0] = f2bf(v.x);
        s[row * 33 + lc + 1] = f2bf(v.y);
        s[row * 33 + lc + 2] = f2bf(v.z);
        s[row * 33 + lc + 3] = f2bf(v.w);
    }
    __syncthreads();
    const int oc = tid >> 3, rr = (tid & 7) * 8;
    u16x8 o;
    #pragma unroll
    for (int i = 0; i < 8; ++i) o[i] = s[(rr + i) * 33 + oc];
    *(u16x8*)(oute + (size_t)(c0 + oc) * R + r0 + rr) = o;
}

// ---------------------------------------------------------------------------
// Grouped MFMA GEMM1: H = relu(Xg @ W1t^T + b1).
// BM=256 x BN=128, BK=32, 512 thr (8 waves 4Mx2N, wave 64x64, acc[4][4]).
// r6 schedule: 2-buffer, issue-after-read-barrier, counted vmcnt(3).
// 3 glds/thread/K-step -> MFMA:glds = 16:3 (r6 was 16:4). LDS 49 KB,
// 2 blocks/CU. grid = 32 n * WSL256; n_t&7 = XCD.
// ---------------------------------------------------------------------------
__global__ __launch_bounds__(512, 2) void k_ffn1(
    const u16* __restrict__ xb,     // [T][1024]
    const u16* __restrict__ W1t,    // [E][4096][1024]
    const float* __restrict__ b1,
    const int* __restrict__ counts, const int* __restrict__ offsets,
    const int* __restrict__ list_tok,
    u16* __restrict__ H)            // [NPAIR][4096]
{
    const int bid = blockIdx.x;
    const int n_t = (bid & 7) | (((bid >> 3) & 3) << 3);   // 0..31, n_t&7 = XCD
    const int wsl = bid >> 5;

    int e, m_t;
    if (!work_map256(counts, wsl, e, m_t)) return;
    const int cnt  = counts[e];
    const int base = offsets[e];
    const int m0   = m_t * 256;
    const int n0   = n_t * 128;
    const u16* __restrict__ Be = W1t + (size_t)e * (HID * D_MODEL);

    __shared__ __align__(16) u16 SA[2 * 8192];  // 2 x (256 x 32) = 32 KB
    __shared__ __align__(16) u16 SB[2 * 4096];  // 2 x (128 x 32) = 16 KB
    __shared__ int stok[256];

    const int tid = threadIdx.x;
    if (tid < 256) stok[tid] = list_tok[base + min(m0 + tid, cnt - 1)];
    __syncthreads();

    int ar0, ak0, ar1, ak1;
    chunk_map(tid, ar0, ak0);          // A rows   0..127 / B rows 0..127
    chunk_map(tid + 512, ar1, ak1);    // A rows 128..255
    const u16* Asrc0 = xb + (size_t)stok[ar0] * D_MODEL + ak0;
    const u16* Asrc1 = xb + (size_t)stok[ar1] * D_MODEL + ak1;
    const u16* Bsrc  = Be + (size_t)(n0 + ar0) * D_MODEL + ak0;

    const int lane = tid & 63, lr = lane & 15, hk = lane >> 4;
    const int w = tid >> 6, wm = w >> 1, wn = w & 1;        // 4M x 2N
    const int colb  = ((((lr & 1) << 2) + hk) ^ (lr >> 1)) << 4;
    const int baseA = ((wm * 32 + (lr >> 1)) << 7) + colb;  // wave rows wm*64
    const int baseB = ((wn * 32 + (lr >> 1)) << 7) + colb;  // wave cols wn*64

    float bias[4];
    #pragma unroll
    for (int j = 0; j < 4; ++j) bias[j] = b1[(size_t)e * HID + n0 + wn * 64 + j * 16 + lr];

    f32x4 acc[4][4] = {};

    auto STAGE = [&](int s, int t) {
        const int kt = t * 32;
        char* Ab = (char*)(SA + s * 8192);
        char* Bb = (char*)(SB + s * 4096);
        glds16(Asrc0 + kt, Ab + tid * 16);
        glds16(Asrc1 + kt, Ab + (tid + 512) * 16);
        glds16(Bsrc  + kt, Bb + tid * 16);
    };
    auto COMPUTE = [&](int s) {
        const char* Ab = (const char*)(SA + s * 8192);
        const char* Bb = (const char*)(SB + s * 4096);
        bf16x8 a[4], b[4];
        #pragma unroll
        for (int i = 0; i < 4; ++i) a[i] = *(const bf16x8*)(Ab + baseA + i * 1024);
        #pragma unroll
        for (int j = 0; j < 4; ++j) b[j] = *(const bf16x8*)(Bb + baseB + j * 1024);
        #pragma unroll
        for (int i = 0; i < 4; ++i)
            #pragma unroll
            for (int j = 0; j < 4; ++j)
                acc[i][j] = __builtin_amdgcn_mfma_f32_16x16x32_bf16(a[i], b[j], acc[i][j], 0, 0, 0);
    };

    const int NT = D_MODEL / 32;                // 32
    STAGE(0, 0);
    STAGE(1, 1);
    for (int t = 0; t < NT; ++t) {
        if (t < NT - 1) { asm volatile("s_waitcnt vmcnt(3)" ::: "memory"); }
        else            { asm volatile("s_waitcnt vmcnt(0)" ::: "memory"); }
        __builtin_amdgcn_s_barrier();
        __builtin_amdgcn_sched_barrier(0);
        COMPUTE(t & 1);
        __builtin_amdgcn_sched_barrier(0);
        __builtin_amdgcn_s_barrier();           // all reads of buf (t&1) done
        if (t + 2 < NT) STAGE(t & 1, t + 2);
    }

    #pragma unroll
    for (int i = 0; i < 4; ++i) {
        #pragma unroll
        for (int g = 0; g < 4; ++g) {
            const int m = m0 + wm * 64 + i * 16 + hk * 4 + g;
            if (m < cnt) {
                u16* dst = H + (size_t)(base + m) * HID + n0 + wn * 64 + lr;
                #pragma unroll
                for (int j = 0; j < 4; ++j)
                    dst[j * 16] = f2bf(fmaxf(acc[i][j][g] + bias[j], 0.f));
            }
        }
    }
}

// ---------------------------------------------------------------------------
// Grouped MFMA GEMM2: out += gate*(H @ W2t^T + b2). 128x128 tile, BK=64:
// half the barrier/vmcnt events of r6, 2x bytes in flight (vmcnt(8) counted).
// 256 thr (4 waves 2Mx2N, wave 64x64), 2 buffers (65 KB -> 2 blocks/CU).
// Accumulation order ksub0->ksub1 == two BK=32 steps (bit-identical to r6).
// grid = 8 n * WSLOTS; n_t = XCD-exclusive W2t panel.
// ---------------------------------------------------------------------------
__global__ __launch_bounds__(256, 2) void k_ffn2(
    const u16* __restrict__ Hb,     // [NPAIR][4096]
    const u16* __restrict__ W2t,    // [E][1024][4096]
    const float* __restrict__ b2,
    const int* __restrict__ counts, const int* __restrict__ offsets,
    const int* __restrict__ list_tok, const float* __restrict__ list_gate,
    float* __restrict__ out)
{
    const int bid = blockIdx.x;
    const int n_t = bid & 7;
    const int wsl = bid >> 3;

    int e, m_t;
    if (!work_map(counts, wsl, e, m_t)) return;
    const int cnt  = counts[e];
    const int base = offsets[e];
    const int m0   = m_t * 128;
    const int n0   = n_t * 128;
    const u16* __restrict__ Be = W2t + (size_t)e * (D_MODEL * HID);

    __shared__ __align__(16) u16 SA[2 * 8192];  // 2 x (128 x 64) = 32 KB
    __shared__ __align__(16) u16 SB[2 * 8192];  // 32 KB
    __shared__ int   s_tok[128];
    __shared__ float s_gate[128];

    const int tid = threadIdx.x;
    if (tid < 128) {
        const int sl = base + min(m0 + tid, cnt - 1);
        s_tok[tid]  = list_tok[sl];
        s_gate[tid] = list_gate[sl];
    }
    __syncthreads();

    // BK=64 stage map: slot s = g*256+tid -> row = s>>3, u = (s&7)^(row&7)
    const u16* Asrc[4];
    const u16* Bsrc[4];
    #pragma unroll
    for (int g = 0; g < 4; ++g) {
        const int s = g * 256 + tid;
        const int r = s >> 3;
        const int u = (s & 7) ^ (r & 7);
        Asrc[g] = Hb + (size_t)(base + min(m0 + r, cnt - 1)) * HID + u * 8;
        Bsrc[g] = Be + (size_t)(n0 + r) * HID + u * 8;
    }

    const int lane = tid & 63, lr = lane & 15, hk = lane >> 4;
    const int w = tid >> 6, wm = w >> 1, wn = w & 1;
    // BK=64 read: off = row*128 + ((v ^ (row&7))*16), row&7 = lr&7, v = ksub*4+hk
    const int baseA = (wm * 64 + lr) * 128 + ((hk ^ (lr & 7)) << 4);
    const int baseB = (wn * 64 + lr) * 128 + ((hk ^ (lr & 7)) << 4);

    float bias[4];
    #pragma unroll
    for (int j = 0; j < 4; ++j) bias[j] = b2[(size_t)e * D_MODEL + n0 + wn * 64 + j * 16 + lr];

    f32x4 acc[4][4] = {};

    auto STAGE = [&](int s, int t) {
        const int kt = t * 64;
        char* Ab = (char*)(SA + s * 8192);
        char* Bb = (char*)(SB + s * 8192);
        #pragma unroll
        for (int g = 0; g < 4; ++g) glds16(Asrc[g] + kt, Ab + (g * 256 + tid) * 16);
        #pragma unroll
        for (int g = 0; g < 4; ++g) glds16(Bsrc[g] + kt, Bb + (g * 256 + tid) * 16);
    };
    auto COMPUTE = [&](int s) {
        const char* Ab = (const char*)(SA + s * 8192);
        const char* Bb = (const char*)(SB + s * 8192);
        #pragma unroll
        for (int ks = 0; ks < 2; ++ks) {
            const int kx = ks * 64;             // XOR 64 flips v-bit2 (ksub)
            bf16x8 a[4], b[4];
            #pragma unroll
            for (int i = 0; i < 4; ++i) a[i] = *(const bf16x8*)(Ab + ((baseA + i * 2048) ^ kx));
            #pragma unroll
            for (int j = 0; j < 4; ++j) b[j] = *(const bf16x8*)(Bb + ((baseB + j * 2048) ^ kx));
            #pragma unroll
            for (int i = 0; i < 4; ++i)
                #pragma unroll
                for (int j = 0; j < 4; ++j)
                    acc[i][j] = __builtin_amdgcn_mfma_f32_16x16x32_bf16(a[i], b[j], acc[i][j], 0, 0, 0);
        }
    };

    const int NT = HID / 64;                    // 64
    STAGE(0, 0);
    STAGE(1, 1);
    for (int t = 0; t < NT; ++t) {
        if (t < NT - 1) { asm volatile("s_waitcnt vmcnt(8)" ::: "memory"); }
        else            { asm volatile("s_waitcnt vmcnt(0)" ::: "memory"); }
        __builtin_amdgcn_s_barrier();
        __builtin_amdgcn_sched_barrier(0);
        COMPUTE(t & 1);
        __builtin_amdgcn_sched_barrier(0);
        __builtin_amdgcn_s_barrier();
        if (t + 2 < NT) STAGE(t & 1, t + 2);
    }

    #pragma unroll
    for (int i = 0; i < 4; ++i) {
        #pragma unroll
        for (int g = 0; g < 4; ++g) {
            const int m = m0 + wm * 64 + i * 16 + hk * 4 + g;
            if (m < cnt) {
                const int   mm = m - m0;
                const int   tk = s_tok[mm];
                const float gt = s_gate[mm];
                float* dst = out + (size_t)tk * D_MODEL + n0 + wn * 64 + lr;
                #pragma unroll
                for (int j = 0; j < 4; ++j)
                    unsafeAtomicAdd(dst + j * 16, gt * (acc[i][j][g] + bias[j]));
            }
        }
    }
}

// ---------------------------------------------------------------------------
extern "C" void kernel_launch(void* const* d_in, const int* in_sizes, int n_in,
                              void* d_out, int out_size, void* d_ws, size_t ws_size,
                              hipStream_t stream)
{
    const float* x     = (const float*)d_in[0];
    const float* noise = (const float*)d_in[1];
    const float* Wr    = (const float*)d_in[2];
    const float* br    = (const float*)d_in[3];
    const float* Wn    = (const float*)d_in[4];
    const float* bn    = (const float*)d_in[5];
    const float* W1    = (const float*)d_in[6];
    const float* b1    = (const float*)d_in[7];
    const float* W2    = (const float*)d_in[8];
    const float* b2    = (const float*)d_in[9];
    float* out = (float*)d_out;

    char* ws = (char*)d_ws;
    int*   counts    = (int*)(ws + WS_COUNTS);
    int*   cursor    = (int*)(ws + WS_CURSOR);
    int*   offsets   = (int*)(ws + WS_OFFSETS);
    int*   tok_e     = (int*)(ws + WS_TOKE);
    float* tok_g     = (float*)(ws + WS_TOKG);
    int*   list_tok  = (int*)(ws + WS_LTOK);
    float* list_gate = (float*)(ws + WS_LGATE);
    u16*   xb        = (u16*)(ws + WS_XB);
    u16*   Wb        = (u16*)(ws + WS_WB);
    u16*   Hb        = (u16*)(ws + WS_H);

    hipMemsetAsync(ws, 0, 128, stream);
    hipMemsetAsync(d_out, 0, (size_t)out_size * sizeof(float), stream);

    k_cvtT<<<dim3(HID / 32, D_MODEL / 64, N_EXP), 256, 0, stream>>>(W1, Wb, D_MODEL, HID);
    k_router<<<T_TOK, 256, 0, stream>>>(x, noise, Wr, br, Wn, bn, counts, tok_e, tok_g, xb);
    k_prefix<<<1, 64, 0, stream>>>(counts, offsets);
    k_scatter<<<NPAIR / 256, 256, 0, stream>>>(tok_e, tok_g, offsets, cursor,
                                               list_tok, list_gate);

    k_ffn1<<<32 * WSL256, 512, 0, stream>>>(xb, Wb, b1, counts, offsets,
                                            list_tok, Hb);

    k_cvtT<<<dim3(D_MODEL / 32, HID / 64, N_EXP), 256, 0, stream>>>(W2, Wb, HID, D_MODEL);
    k_ffn2<<<8 * WSLOTS, 256, 0, stream>>>(Hb, Wb, b2, counts, offsets,
                                           list_tok, list_gate, out);
}

// Round 12
// 465.942 us; speedup vs baseline: 1.1125x; 1.0792x over previous
//
#include <hip/hip_runtime.h>
#include <hip/hip_bf16.h>
#include <cstdint>
#include <cstddef>

#define D_MODEL 1024
#define N_EXP   8
#define HID     4096
#define T_TOK   4096          // B*S
#define NPAIR   (T_TOK * 2)   // top-2
#define WSLOTS  72            // max m-tiles total: 8192/128 + 7 = 71

// ---------------- workspace layout (bytes) ----------------
#define WS_COUNTS   0
#define WS_CURSOR   32
#define WS_OFFSETS  64
#define WS_TOKE     128                       // tok_e[T][2] int
#define WS_TOKG     32896                     // tok_g[T][2] float
#define WS_LTOK     65664                     // list_tok[NPAIR] int
#define WS_LGATE    98432                     // list_gate[NPAIR] float
#define WS_XB       131328                    // xb[T][1024] bf16        (8 MB)
#define WS_WB       (WS_XB + 8388608)         // W1t bf16                (64 MB)
#define WS_H        (WS_WB + 67108864)        // H[NPAIR][4096] bf16     (64 MB)
#define WS_W2       (WS_H + 67108864)         // W2t bf16 (if ws allows) (64 MB)
#define WS_NEEDED   ((size_t)WS_W2 + 67108864)

typedef __attribute__((ext_vector_type(8))) short bf16x8;
typedef __attribute__((ext_vector_type(4))) float f32x4;
typedef __attribute__((ext_vector_type(8))) unsigned short u16x8;
typedef unsigned short u16;

__device__ __forceinline__ u16 f2bf(float f) {
    unsigned u = __float_as_uint(f);
    u += 0x7FFFu + ((u >> 16) & 1u);          // RNE
    return (u16)(u >> 16);
}

__device__ __forceinline__ void glds16(const void* g, void* l) {
    __builtin_amdgcn_global_load_lds(
        (const __attribute__((address_space(1))) void*)g,
        (__attribute__((address_space(3))) void*)l, 16, 0, 0);
}

// Swizzled-stage chunk map (validated r3/r6: conflicts 0, bit-exact output).
__device__ __forceinline__ void chunk_map(int c, int& row, int& kc) {
    const int line = c >> 3, c8 = c & 7, u = c8 ^ (line & 7);
    row = line * 2 + (u >> 2);
    kc  = (u & 3) * 8;                        // ushort offset in 32-wide K window
}

// compact worklist: slot w -> (expert, m_tile). uniform per block.
__device__ __forceinline__ bool work_map(const int* counts, int w,
                                         int& e, int& m_t) {
    int tot = 0; e = -1; m_t = 0;
    #pragma unroll
    for (int i = 0; i < N_EXP; ++i) {
        const int tl = (counts[i] + 127) >> 7;
        if (e < 0 && w < tot + tl) { e = i; m_t = w - tot; }
        tot += tl;
    }
    return e >= 0;
}

// ---------------------------------------------------------------------------
// Router (validated) + fused x -> bf16 emission (validated r4)
// ---------------------------------------------------------------------------
__global__ __launch_bounds__(256) void k_router(
    const float* __restrict__ x, const float* __restrict__ noise,
    const float* __restrict__ Wr, const float* __restrict__ br,
    const float* __restrict__ Wn, const float* __restrict__ bn,
    int* __restrict__ counts, int* __restrict__ tok_e, float* __restrict__ tok_g,
    u16* __restrict__ xb)
{
    const int t   = blockIdx.x;
    const int tid = threadIdx.x;
    const int e   = tid & 7;
    const int g   = tid >> 3;
    const float* xr = x + (size_t)t * D_MODEL;

    {
        const float4 v4 = *(const float4*)(xr + tid * 4);
        ushort4 o;
        o.x = f2bf(v4.x); o.y = f2bf(v4.y); o.z = f2bf(v4.z); o.w = f2bf(v4.w);
        *(ushort4*)(xb + (size_t)t * D_MODEL + tid * 4) = o;
    }

    float ar = 0.f, an = 0.f;
    const int ibase = g * 32;
    #pragma unroll 8
    for (int j = 0; j < 32; ++j) {
        const int i = ibase + j;
        const float xv = xr[i];
        ar = fmaf(xv, Wr[i * 8 + e], ar);
        an = fmaf(xv, Wn[i * 8 + e], an);
    }

    __shared__ float sR[256], sN[256];
    sR[tid] = ar; sN[tid] = an;
    __syncthreads();
    for (int off = 128; off >= 8; off >>= 1) {
        if (tid < off) { sR[tid] += sR[tid + off]; sN[tid] += sN[tid + off]; }
        __syncthreads();
    }

    __shared__ float lg[8];
    if (tid < 8) {
        const float z  = sN[tid] + bn[tid];
        const float sp = fmaxf(z, 0.f) + log1pf(expf(-fabsf(z)));
        lg[tid] = sR[tid] + br[tid] + sp * noise[t * 8 + tid];
    }
    __syncthreads();

    if (tid == 0) {
        float v0 = -INFINITY, v1 = -INFINITY;
        int   i0 = 0,         i1 = 0;
        #pragma unroll
        for (int ee = 0; ee < 8; ++ee) {
            const float v = lg[ee];
            if (v > v0)      { v1 = v0; i1 = i0; v0 = v; i0 = ee; }
            else if (v > v1) { v1 = v;  i1 = ee; }
        }
        const float ew  = expf(v1 - v0);
        const float inv = 1.f / (1.f + ew);
        tok_e[t * 2 + 0] = i0;
        tok_e[t * 2 + 1] = i1;
        tok_g[t * 2 + 0] = inv;
        tok_g[t * 2 + 1] = ew * inv;
        atomicAdd(&counts[i0], 1);
        atomicAdd(&counts[i1], 1);
    }
}

__global__ void k_prefix(const int* __restrict__ counts, int* __restrict__ offsets)
{
    if (threadIdx.x == 0 && blockIdx.x == 0) {
        int acc = 0;
        #pragma unroll
        for (int e = 0; e < N_EXP; ++e) { offsets[e] = acc; acc += counts[e]; }
    }
}

__global__ __launch_bounds__(256) void k_scatter(
    const int* __restrict__ tok_e, const float* __restrict__ tok_g,
    const int* __restrict__ offsets, int* __restrict__ cursor,
    int* __restrict__ list_tok, float* __restrict__ list_gate)
{
    const int gid = blockIdx.x * 256 + threadIdx.x;
    if (gid >= NPAIR) return;
    const int e = tok_e[gid];
    const int p = atomicAdd(&cursor[e], 1);
    const int slot = offsets[e] + p;
    list_tok[slot]  = gid >> 1;
    list_gate[slot] = tok_g[gid];
}

// ---------------------------------------------------------------------------
// Per-expert transpose+convert v3: f32 [E][R][C] -> bf16 [E][C][R].
// 128x128 tile, bf16 staged in LDS [128][134] (ushort2 stores, 4-al).
// Reads: 128 rows x 512 B runs; writes: 128 cols x 256 B runs (u16x8).
// 4x better DRAM locality both sides vs the 64x32 version.
// ---------------------------------------------------------------------------
__global__ __launch_bounds__(256) void k_cvtT(
    const float* __restrict__ in, u16* __restrict__ outp, int R, int C)
{
    const size_t esz = (size_t)R * C;
    const float* ine = in + (size_t)blockIdx.z * esz;
    u16* oute = outp + (size_t)blockIdx.z * esz;
    const int c0 = blockIdx.x * 128, r0 = blockIdx.y * 128;

    __shared__ u16 s[128 * 134];
    const int tid = threadIdx.x;

    // load: 128 rows x 32 float4 (512 B per row, fully coalesced)
    #pragma unroll
    for (int p = 0; p < 16; ++p) {
        const int idx = p * 256 + tid;
        const int row = idx >> 5, c4 = (idx & 31) * 4;
        const float4 v = *(const float4*)(ine + (size_t)(r0 + row) * C + c0 + c4);
        ushort2 lo, hi;
        lo.x = f2bf(v.x); lo.y = f2bf(v.y);
        hi.x = f2bf(v.z); hi.y = f2bf(v.w);
        *(ushort2*)(s + row * 134 + c4)     = lo;
        *(ushort2*)(s + row * 134 + c4 + 2) = hi;
    }
    __syncthreads();

    // store: 128 cols x 16 u16x8 chunks (256 B per col run along R)
    #pragma unroll
    for (int p = 0; p < 8; ++p) {
        const int idx = p * 256 + tid;
        const int col = idx >> 4, r8 = (idx & 15) * 8;
        u16x8 o;
        #pragma unroll
        for (int i = 0; i < 8; ++i) o[i] = s[(r8 + i) * 134 + col];
        *(u16x8*)(oute + (size_t)(c0 + col) * R + r0 + r8) = o;
    }
}

// ---------------------------------------------------------------------------
// Grouped MFMA GEMM1: H = relu(Xg @ W1t^T + b1).  (r6-validated, verbatim)
// ---------------------------------------------------------------------------
__global__ __launch_bounds__(256, 4) void k_ffn1(
    const u16* __restrict__ xb,     // [T][1024]
    const u16* __restrict__ W1t,    // [E][4096][1024]
    const float* __restrict__ b1,
    const int* __restrict__ counts, const int* __restrict__ offsets,
    const int* __restrict__ list_tok,
    u16* __restrict__ H)            // [NPAIR][4096]
{
    const int bid = blockIdx.x;
    const int n_t = (bid & 7) | (((bid >> 3) & 3) << 3);   // 0..31, n_t&7 = XCD
    const int wsl = bid >> 5;

    int e, m_t;
    if (!work_map(counts, wsl, e, m_t)) return;
    const int cnt  = counts[e];
    const int base = offsets[e];
    const int m0   = m_t * 128;
    const int n0   = n_t * 128;
    const u16* __restrict__ Be = W1t + (size_t)e * (HID * D_MODEL);

    __shared__ __align__(16) u16 SA[2 * 4096];  // 2 x (128 x 32) bf16 = 16 KB
    __shared__ __align__(16) u16 SB[2 * 4096];
    __shared__ int stok[128];

    const int tid = threadIdx.x;
    if (tid < 128) stok[tid] = list_tok[base + min(m0 + tid, cnt - 1)];
    __syncthreads();

    int ar0, ak0, ar1, ak1;
    chunk_map(tid, ar0, ak0);
    chunk_map(tid + 256, ar1, ak1);
    const u16* Asrc0 = xb + (size_t)stok[ar0] * D_MODEL + ak0;
    const u16* Asrc1 = xb + (size_t)stok[ar1] * D_MODEL + ak1;
    const u16* Bsrc0 = Be + (size_t)(n0 + ar0) * D_MODEL + ak0;
    const u16* Bsrc1 = Be + (size_t)(n0 + ar1) * D_MODEL + ak1;

    const int lane = tid & 63, lr = lane & 15, hk = lane >> 4;
    const int w = tid >> 6, wm = w >> 1, wn = w & 1;
    const int colb  = ((((lr & 1) << 2) + hk) ^ (lr >> 1)) << 4;
    const int baseA = ((wm * 32 + (lr >> 1)) << 7) + colb;
    const int baseB = ((wn * 32 + (lr >> 1)) << 7) + colb;

    float bias[4];
    #pragma unroll
    for (int j = 0; j < 4; ++j) bias[j] = b1[(size_t)e * HID + n0 + wn * 64 + j * 16 + lr];

    f32x4 acc[4][4] = {};

    auto STAGE = [&](int s, int t) {
        const int kt = t * 32;
        char* Ab = (char*)SA + s * 8192;
        char* Bb = (char*)SB + s * 8192;
        glds16(Asrc0 + kt, Ab + tid * 16);
        glds16(Asrc1 + kt, Ab + (tid + 256) * 16);
        glds16(Bsrc0 + kt, Bb + tid * 16);
        glds16(Bsrc1 + kt, Bb + (tid + 256) * 16);
    };
    auto COMPUTE = [&](int s) {
        const char* Ab = (const char*)SA + s * 8192;
        const char* Bb = (const char*)SB + s * 8192;
        bf16x8 a[4], b[4];
        #pragma unroll
        for (int i = 0; i < 4; ++i) a[i] = *(const bf16x8*)(Ab + baseA + i * 1024);
        #pragma unroll
        for (int j = 0; j < 4; ++j) b[j] = *(const bf16x8*)(Bb + baseB + j * 1024);
        #pragma unroll
        for (int i = 0; i < 4; ++i)
            #pragma unroll
            for (int j = 0; j < 4; ++j)
                acc[i][j] = __builtin_amdgcn_mfma_f32_16x16x32_bf16(a[i], b[j], acc[i][j], 0, 0, 0);
    };

    const int NT = D_MODEL / 32;                // 32
    STAGE(0, 0);
    STAGE(1, 1);
    for (int t = 0; t < NT; ++t) {
        if (t < NT - 1) { asm volatile("s_waitcnt vmcnt(4)" ::: "memory"); }
        else            { asm volatile("s_waitcnt vmcnt(0)" ::: "memory"); }
        __builtin_amdgcn_s_barrier();
        __builtin_amdgcn_sched_barrier(0);
        COMPUTE(t & 1);
        __builtin_amdgcn_sched_barrier(0);
        __builtin_amdgcn_s_barrier();           // all reads of buf (t&1) done
        if (t + 2 < NT) STAGE(t & 1, t + 2);    // overwrite it for t+2
    }

    #pragma unroll
    for (int i = 0; i < 4; ++i) {
        #pragma unroll
        for (int g = 0; g < 4; ++g) {
            const int m = m0 + wm * 64 + i * 16 + hk * 4 + g;
            if (m < cnt) {
                u16* dst = H + (size_t)(base + m) * HID + n0 + wn * 64 + lr;
                #pragma unroll
                for (int j = 0; j < 4; ++j)
                    dst[j * 16] = f2bf(fmaxf(acc[i][j][g] + bias[j], 0.f));
            }
        }
    }
}

// ---------------------------------------------------------------------------
// Grouped MFMA GEMM2: out += gate*(H @ W2t^T + b2).  (r6-validated, verbatim)
// ---------------------------------------------------------------------------
__global__ __launch_bounds__(256, 4) void k_ffn2(
    const u16* __restrict__ Hb,     // [NPAIR][4096]
    const u16* __restrict__ W2t,    // [E][1024][4096]
    const float* __restrict__ b2,
    const int* __restrict__ counts, const int* __restrict__ offsets,
    const int* __restrict__ list_tok, const float* __restrict__ list_gate,
    float* __restrict__ out)
{
    const int bid = blockIdx.x;
    const int n_t = bid & 7;
    const int wsl = bid >> 3;

    int e, m_t;
    if (!work_map(counts, wsl, e, m_t)) return;
    const int cnt  = counts[e];
    const int base = offsets[e];
    const int m0   = m_t * 128;
    const int n0   = n_t * 128;
    const u16* __restrict__ Be = W2t + (size_t)e * (D_MODEL * HID);

    __shared__ __align__(16) u16 SA[2 * 4096];
    __shared__ __align__(16) u16 SB[2 * 4096];
    __shared__ int   s_tok[128];
    __shared__ float s_gate[128];

    const int tid = threadIdx.x;
    if (tid < 128) {
        const int sl = base + min(m0 + tid, cnt - 1);
        s_tok[tid]  = list_tok[sl];
        s_gate[tid] = list_gate[sl];
    }
    __syncthreads();

    int ar0, ak0, ar1, ak1;
    chunk_map(tid, ar0, ak0);
    chunk_map(tid + 256, ar1, ak1);
    const u16* Asrc0 = Hb + (size_t)(base + min(m0 + ar0, cnt - 1)) * HID + ak0;
    const u16* Asrc1 = Hb + (size_t)(base + min(m0 + ar1, cnt - 1)) * HID + ak1;
    const u16* Bsrc0 = Be + (size_t)(n0 + ar0) * HID + ak0;
    const u16* Bsrc1 = Be + (size_t)(n0 + ar1) * HID + ak1;

    const int lane = tid & 63, lr = lane & 15, hk = lane >> 4;
    const int w = tid >> 6, wm = w >> 1, wn = w & 1;
    const int colb  = ((((lr & 1) << 2) + hk) ^ (lr >> 1)) << 4;
    const int baseA = ((wm * 32 + (lr >> 1)) << 7) + colb;
    const int baseB = ((wn * 32 + (lr >> 1)) << 7) + colb;

    float bias[4];
    #pragma unroll
    for (int j = 0; j < 4; ++j) bias[j] = b2[(size_t)e * D_MODEL + n0 + wn * 64 + j * 16 + lr];

    f32x4 acc[4][4] = {};

    auto STAGE = [&](int s, int t) {
        const int kt = t * 32;
        char* Ab = (char*)SA + s * 8192;
        char* Bb = (char*)SB + s * 8192;
        glds16(Asrc0 + kt, Ab + tid * 16);
        glds16(Asrc1 + kt, Ab + (tid + 256) * 16);
        glds16(Bsrc0 + kt, Bb + tid * 16);
        glds16(Bsrc1 + kt, Bb + (tid + 256) * 16);
    };
    auto COMPUTE = [&](int s) {
        const char* Ab = (const char*)SA + s * 8192;
        const char* Bb = (const char*)SB + s * 8192;
        bf16x8 a[4], b[4];
        #pragma unroll
        for (int i = 0; i < 4; ++i) a[i] = *(const bf16x8*)(Ab + baseA + i * 1024);
        #pragma unroll
        for (int j = 0; j < 4; ++j) b[j] = *(const bf16x8*)(Bb + baseB + j * 1024);
        #pragma unroll
        for (int i = 0; i < 4; ++i)
            #pragma unroll
            for (int j = 0; j < 4; ++j)
                acc[i][j] = __builtin_amdgcn_mfma_f32_16x16x32_bf16(a[i], b[j], acc[i][j], 0, 0, 0);
    };

    const int NT = HID / 32;                    // 128
    STAGE(0, 0);
    STAGE(1, 1);
    for (int t = 0; t < NT; ++t) {
        if (t < NT - 1) { asm volatile("s_waitcnt vmcnt(4)" ::: "memory"); }
        else            { asm volatile("s_waitcnt vmcnt(0)" ::: "memory"); }
        __builtin_amdgcn_s_barrier();
        __builtin_amdgcn_sched_barrier(0);
        COMPUTE(t & 1);
        __builtin_amdgcn_sched_barrier(0);
        __builtin_amdgcn_s_barrier();
        if (t + 2 < NT) STAGE(t & 1, t + 2);
    }

    #pragma unroll
    for (int i = 0; i < 4; ++i) {
        #pragma unroll
        for (int g = 0; g < 4; ++g) {
            const int m = m0 + wm * 64 + i * 16 + hk * 4 + g;
            if (m < cnt) {
                const int   mm = m - m0;
                const int   tk = s_tok[mm];
                const float gt = s_gate[mm];
                float* dst = out + (size_t)tk * D_MODEL + n0 + wn * 64 + lr;
                #pragma unroll
                for (int j = 0; j < 4; ++j)
                    unsafeAtomicAdd(dst + j * 16, gt * (acc[i][j][g] + bias[j]));
            }
        }
    }
}

// ---------------------------------------------------------------------------
extern "C" void kernel_launch(void* const* d_in, const int* in_sizes, int n_in,
                              void* d_out, int out_size, void* d_ws, size_t ws_size,
                              hipStream_t stream)
{
    const float* x     = (const float*)d_in[0];
    const float* noise = (const float*)d_in[1];
    const float* Wr    = (const float*)d_in[2];
    const float* br    = (const float*)d_in[3];
    const float* Wn    = (const float*)d_in[4];
    const float* bn    = (const float*)d_in[5];
    const float* W1    = (const float*)d_in[6];
    const float* b1    = (const float*)d_in[7];
    const float* W2    = (const float*)d_in[8];
    const float* b2    = (const float*)d_in[9];
    float* out = (float*)d_out;

    char* ws = (char*)d_ws;
    int*   counts    = (int*)(ws + WS_COUNTS);
    int*   cursor    = (int*)(ws + WS_CURSOR);
    int*   offsets   = (int*)(ws + WS_OFFSETS);
    int*   tok_e     = (int*)(ws + WS_TOKE);
    float* tok_g     = (float*)(ws + WS_TOKG);
    int*   list_tok  = (int*)(ws + WS_LTOK);
    float* list_gate = (float*)(ws + WS_LGATE);
    u16*   xb        = (u16*)(ws + WS_XB);
    u16*   W1b       = (u16*)(ws + WS_WB);
    u16*   Hb        = (u16*)(ws + WS_H);

    const bool big = (ws_size >= WS_NEEDED);
    u16* W2b = big ? (u16*)(ws + WS_W2) : W1b;   // separate buffer if ws allows

    hipMemsetAsync(ws, 0, 128, stream);
    hipMemsetAsync(d_out, 0, (size_t)out_size * sizeof(float), stream);

    k_router<<<T_TOK, 256, 0, stream>>>(x, noise, Wr, br, Wn, bn, counts, tok_e, tok_g, xb);
    k_prefix<<<1, 64, 0, stream>>>(counts, offsets);
    k_scatter<<<NPAIR / 256, 256, 0, stream>>>(tok_e, tok_g, offsets, cursor,
                                               list_tok, list_gate);

    k_cvtT<<<dim3(HID / 128, D_MODEL / 128, N_EXP), 256, 0, stream>>>(W1, W1b, D_MODEL, HID);
    if (big) {
        // convert W2 BEFORE ffn1 so nothing streams between H-write and H-read
        k_cvtT<<<dim3(D_MODEL / 128, HID / 128, N_EXP), 256, 0, stream>>>(W2, W2b, HID, D_MODEL);
        k_ffn1<<<32 * WSLOTS, 256, 0, stream>>>(xb, W1b, b1, counts, offsets,
                                                list_tok, Hb);
    } else {
        k_ffn1<<<32 * WSLOTS, 256, 0, stream>>>(xb, W1b, b1, counts, offsets,
                                                list_tok, Hb);
        k_cvtT<<<dim3(D_MODEL / 128, HID / 128, N_EXP), 256, 0, stream>>>(W2, W2b, HID, D_MODEL);
    }
    k_ffn2<<<8 * WSLOTS, 256, 0, stream>>>(Hb, W2b, b2, counts, offsets,
                                           list_tok, list_gate, out);
}

// Round 13
// 435.521 us; speedup vs baseline: 1.1903x; 1.0698x over previous
//
#include <hip/hip_runtime.h>
#include <hip/hip_bf16.h>
#include <cstdint>
#include <cstddef>

#define D_MODEL 1024
#define N_EXP   8
#define HID     4096
#define T_TOK   4096          // B*S
#define NPAIR   (T_TOK * 2)   // top-2
#define WSLOTS  72            // max m-tiles total: 8192/128 + 7 = 71
#define FFN1B   (32 * WSLOTS) // 2304 ffn1 blocks
#define CVT1B   2048          // W1 cvt blocks (32 x 8 x 8)
#define CVT2B   2048          // W2 cvt blocks (8 x 32 x 8)

// ---------------- workspace layout (bytes) ----------------
#define WS_COUNTS   0
#define WS_CURSOR   32
#define WS_OFFSETS  64
#define WS_TOKE     128                       // tok_e[T][2] int
#define WS_TOKG     32896                     // tok_g[T][2] float
#define WS_LTOK     65664                     // list_tok[NPAIR] int
#define WS_LGATE    98432                     // list_gate[NPAIR] float
#define WS_XB       131328                    // xb[T][1024] bf16        (8 MB)
#define WS_WB       (WS_XB + 8388608)         // W1t bf16                (64 MB)
#define WS_H        (WS_WB + 67108864)        // H[NPAIR][4096] bf16     (64 MB)
#define WS_W2       (WS_H + 67108864)         // W2t bf16 (if ws allows) (64 MB)
#define WS_NEEDED   ((size_t)WS_W2 + 67108864)

typedef __attribute__((ext_vector_type(8))) short bf16x8;
typedef __attribute__((ext_vector_type(4))) float f32x4;
typedef __attribute__((ext_vector_type(8))) unsigned short u16x8;
typedef unsigned short u16;

__device__ __forceinline__ u16 f2bf(float f) {
    unsigned u = __float_as_uint(f);
    u += 0x7FFFu + ((u >> 16) & 1u);          // RNE
    return (u16)(u >> 16);
}

__device__ __forceinline__ void glds16(const void* g, void* l) {
    __builtin_amdgcn_global_load_lds(
        (const __attribute__((address_space(1))) void*)g,
        (__attribute__((address_space(3))) void*)l, 16, 0, 0);
}

// Swizzled-stage chunk map (validated r3/r6: conflicts 0, bit-exact output).
__device__ __forceinline__ void chunk_map(int c, int& row, int& kc) {
    const int line = c >> 3, c8 = c & 7, u = c8 ^ (line & 7);
    row = line * 2 + (u >> 2);
    kc  = (u & 3) * 8;                        // ushort offset in 32-wide K window
}

// compact worklist: slot w -> (expert, m_tile). uniform per block.
__device__ __forceinline__ bool work_map(const int* counts, int w,
                                         int& e, int& m_t) {
    int tot = 0; e = -1; m_t = 0;
    #pragma unroll
    for (int i = 0; i < N_EXP; ++i) {
        const int tl = (counts[i] + 127) >> 7;
        if (e < 0 && w < tot + tl) { e = i; m_t = w - tot; }
        tot += tl;
    }
    return e >= 0;
}

// ---------------------------------------------------------------------------
// Transpose+convert tile body (v3, validated r12): f32 [R][C] -> bf16 [C][R],
// 128x128 tile. s = 34304-byte LDS scratch (u16[128*134]).
// ---------------------------------------------------------------------------
__device__ __forceinline__ void cvt_tile(
    const float* __restrict__ in, u16* __restrict__ outp, int R, int C,
    int bx, int by, int bz, u16* s)
{
    const size_t esz = (size_t)R * C;
    const float* ine = in + (size_t)bz * esz;
    u16* oute = outp + (size_t)bz * esz;
    const int c0 = bx * 128, r0 = by * 128;
    const int tid = threadIdx.x;

    #pragma unroll
    for (int p = 0; p < 16; ++p) {
        const int idx = p * 256 + tid;
        const int row = idx >> 5, c4 = (idx & 31) * 4;
        const float4 v = *(const float4*)(ine + (size_t)(r0 + row) * C + c0 + c4);
        ushort2 lo, hi;
        lo.x = f2bf(v.x); lo.y = f2bf(v.y);
        hi.x = f2bf(v.z); hi.y = f2bf(v.w);
        *(ushort2*)(s + row * 134 + c4)     = lo;
        *(ushort2*)(s + row * 134 + c4 + 2) = hi;
    }
    __syncthreads();

    #pragma unroll
    for (int p = 0; p < 8; ++p) {
        const int idx = p * 256 + tid;
        const int col = idx >> 4, r8 = (idx & 15) * 8;
        u16x8 o;
        #pragma unroll
        for (int i = 0; i < 8; ++i) o[i] = s[(r8 + i) * 134 + col];
        *(u16x8*)(oute + (size_t)(c0 + col) * R + r0 + r8) = o;
    }
}

// standalone cvt kernel (fallback path)
__global__ __launch_bounds__(256) void k_cvtT(
    const float* __restrict__ in, u16* __restrict__ outp, int R, int C)
{
    __shared__ __align__(16) u16 s[128 * 134];
    cvt_tile(in, outp, R, C, blockIdx.x, blockIdx.y, blockIdx.z, s);
}

// ---------------------------------------------------------------------------
// Merged router + cvtW1. bid < CVT1B: convert W1 [E][1024][4096] -> W1t.
// Else: router for token t = bid - CVT1B (validated body, + x->bf16).
// ---------------------------------------------------------------------------
__global__ __launch_bounds__(256) void k_router_cvt(
    const float* __restrict__ x, const float* __restrict__ noise,
    const float* __restrict__ Wr, const float* __restrict__ br,
    const float* __restrict__ Wn, const float* __restrict__ bn,
    int* __restrict__ counts, int* __restrict__ tok_e, float* __restrict__ tok_g,
    u16* __restrict__ xb,
    const float* __restrict__ W1, u16* __restrict__ W1t)
{
    __shared__ __align__(16) char smem[34816];

    if (blockIdx.x < CVT1B) {
        // W1 cvt grid: (HID/128=32, D_MODEL/128=8, 8)
        const int cb = blockIdx.x;
        cvt_tile(W1, W1t, D_MODEL, HID, cb & 31, (cb >> 5) & 7, cb >> 8,
                 (u16*)smem);
        return;
    }

    float* sR = (float*)smem;            // 256 floats
    float* sN = (float*)(smem + 1024);   // 256 floats
    float* lg = (float*)(smem + 2048);   // 8 floats

    const int t   = blockIdx.x - CVT1B;
    const int tid = threadIdx.x;
    const int e   = tid & 7;
    const int g   = tid >> 3;
    const float* xr = x + (size_t)t * D_MODEL;

    {
        const float4 v4 = *(const float4*)(xr + tid * 4);
        ushort4 o;
        o.x = f2bf(v4.x); o.y = f2bf(v4.y); o.z = f2bf(v4.z); o.w = f2bf(v4.w);
        *(ushort4*)(xb + (size_t)t * D_MODEL + tid * 4) = o;
    }

    float ar = 0.f, an = 0.f;
    const int ibase = g * 32;
    #pragma unroll 8
    for (int j = 0; j < 32; ++j) {
        const int i = ibase + j;
        const float xv = xr[i];
        ar = fmaf(xv, Wr[i * 8 + e], ar);
        an = fmaf(xv, Wn[i * 8 + e], an);
    }

    sR[tid] = ar; sN[tid] = an;
    __syncthreads();
    for (int off = 128; off >= 8; off >>= 1) {
        if (tid < off) { sR[tid] += sR[tid + off]; sN[tid] += sN[tid + off]; }
        __syncthreads();
    }

    if (tid < 8) {
        const float z  = sN[tid] + bn[tid];
        const float sp = fmaxf(z, 0.f) + log1pf(expf(-fabsf(z)));
        lg[tid] = sR[tid] + br[tid] + sp * noise[t * 8 + tid];
    }
    __syncthreads();

    if (tid == 0) {
        float v0 = -INFINITY, v1 = -INFINITY;
        int   i0 = 0,         i1 = 0;
        #pragma unroll
        for (int ee = 0; ee < 8; ++ee) {
            const float v = lg[ee];
            if (v > v0)      { v1 = v0; i1 = i0; v0 = v; i0 = ee; }
            else if (v > v1) { v1 = v;  i1 = ee; }
        }
        const float ew  = expf(v1 - v0);
        const float inv = 1.f / (1.f + ew);
        tok_e[t * 2 + 0] = i0;
        tok_e[t * 2 + 1] = i1;
        tok_g[t * 2 + 0] = inv;
        tok_g[t * 2 + 1] = ew * inv;
        atomicAdd(&counts[i0], 1);
        atomicAdd(&counts[i1], 1);
    }
}

__global__ void k_prefix(const int* __restrict__ counts, int* __restrict__ offsets)
{
    if (threadIdx.x == 0 && blockIdx.x == 0) {
        int acc = 0;
        #pragma unroll
        for (int e = 0; e < N_EXP; ++e) { offsets[e] = acc; acc += counts[e]; }
    }
}

__global__ __launch_bounds__(256) void k_scatter(
    const int* __restrict__ tok_e, const float* __restrict__ tok_g,
    const int* __restrict__ offsets, int* __restrict__ cursor,
    int* __restrict__ list_tok, float* __restrict__ list_gate)
{
    const int gid = blockIdx.x * 256 + threadIdx.x;
    if (gid >= NPAIR) return;
    const int e = tok_e[gid];
    const int p = atomicAdd(&cursor[e], 1);
    const int slot = offsets[e] + p;
    list_tok[slot]  = gid >> 1;
    list_gate[slot] = tok_g[gid];
}

// ---------------------------------------------------------------------------
// Merged ffn1 + (optional) cvtW2.
// bid < FFN1B: grouped MFMA GEMM1 (r6-validated body, verbatim).
// bid >= FFN1B: convert W2 [E][4096][1024] -> W2t (only launched when big ws).
// ---------------------------------------------------------------------------
__global__ __launch_bounds__(256, 4) void k_ffn1m(
    const u16* __restrict__ xb,     // [T][1024]
    const u16* __restrict__ W1t,    // [E][4096][1024]
    const float* __restrict__ b1,
    const int* __restrict__ counts, const int* __restrict__ offsets,
    const int* __restrict__ list_tok,
    u16* __restrict__ H,            // [NPAIR][4096]
    const float* __restrict__ W2, u16* __restrict__ W2t)
{
    __shared__ __align__(16) char smem[34816];

    if (blockIdx.x >= FFN1B) {
        // W2 cvt grid: (D_MODEL/128=8, HID/128=32, 8)
        const int cb = blockIdx.x - FFN1B;
        cvt_tile(W2, W2t, HID, D_MODEL, cb & 7, (cb >> 3) & 31, cb >> 8,
                 (u16*)smem);
        return;
    }

    u16* SA   = (u16*)smem;              // 2 x 4096 u16 = 16 KB
    u16* SB   = (u16*)(smem + 16384);    // 16 KB
    int* stok = (int*)(smem + 32768);    // 512 B

    const int bid = blockIdx.x;
    const int n_t = (bid & 7) | (((bid >> 3) & 3) << 3);   // 0..31, n_t&7 = XCD
    const int wsl = bid >> 5;

    int e, m_t;
    if (!work_map(counts, wsl, e, m_t)) return;
    const int cnt  = counts[e];
    const int base = offsets[e];
    const int m0   = m_t * 128;
    const int n0   = n_t * 128;
    const u16* __restrict__ Be = W1t + (size_t)e * (HID * D_MODEL);

    const int tid = threadIdx.x;
    if (tid < 128) stok[tid] = list_tok[base + min(m0 + tid, cnt - 1)];
    __syncthreads();

    int ar0, ak0, ar1, ak1;
    chunk_map(tid, ar0, ak0);
    chunk_map(tid + 256, ar1, ak1);
    const u16* Asrc0 = xb + (size_t)stok[ar0] * D_MODEL + ak0;
    const u16* Asrc1 = xb + (size_t)stok[ar1] * D_MODEL + ak1;
    const u16* Bsrc0 = Be + (size_t)(n0 + ar0) * D_MODEL + ak0;
    const u16* Bsrc1 = Be + (size_t)(n0 + ar1) * D_MODEL + ak1;

    const int lane = tid & 63, lr = lane & 15, hk = lane >> 4;
    const int w = tid >> 6, wm = w >> 1, wn = w & 1;
    const int colb  = ((((lr & 1) << 2) + hk) ^ (lr >> 1)) << 4;
    const int baseA = ((wm * 32 + (lr >> 1)) << 7) + colb;
    const int baseB = ((wn * 32 + (lr >> 1)) << 7) + colb;

    float bias[4];
    #pragma unroll
    for (int j = 0; j < 4; ++j) bias[j] = b1[(size_t)e * HID + n0 + wn * 64 + j * 16 + lr];

    f32x4 acc[4][4] = {};

    auto STAGE = [&](int s, int t) {
        const int kt = t * 32;
        char* Ab = (char*)SA + s * 8192;
        char* Bb = (char*)SB + s * 8192;
        glds16(Asrc0 + kt, Ab + tid * 16);
        glds16(Asrc1 + kt, Ab + (tid + 256) * 16);
        glds16(Bsrc0 + kt, Bb + tid * 16);
        glds16(Bsrc1 + kt, Bb + (tid + 256) * 16);
    };
    auto COMPUTE = [&](int s) {
        const char* Ab = (const char*)SA + s * 8192;
        const char* Bb = (const char*)SB + s * 8192;
        bf16x8 a[4], b[4];
        #pragma unroll
        for (int i = 0; i < 4; ++i) a[i] = *(const bf16x8*)(Ab + baseA + i * 1024);
        #pragma unroll
        for (int j = 0; j < 4; ++j) b[j] = *(const bf16x8*)(Bb + baseB + j * 1024);
        #pragma unroll
        for (int i = 0; i < 4; ++i)
            #pragma unroll
            for (int j = 0; j < 4; ++j)
                acc[i][j] = __builtin_amdgcn_mfma_f32_16x16x32_bf16(a[i], b[j], acc[i][j], 0, 0, 0);
    };

    const int NT = D_MODEL / 32;                // 32
    STAGE(0, 0);
    STAGE(1, 1);
    for (int t = 0; t < NT; ++t) {
        if (t < NT - 1) { asm volatile("s_waitcnt vmcnt(4)" ::: "memory"); }
        else            { asm volatile("s_waitcnt vmcnt(0)" ::: "memory"); }
        __builtin_amdgcn_s_barrier();
        __builtin_amdgcn_sched_barrier(0);
        COMPUTE(t & 1);
        __builtin_amdgcn_sched_barrier(0);
        __builtin_amdgcn_s_barrier();           // all reads of buf (t&1) done
        if (t + 2 < NT) STAGE(t & 1, t + 2);    // overwrite it for t+2
    }

    #pragma unroll
    for (int i = 0; i < 4; ++i) {
        #pragma unroll
        for (int g = 0; g < 4; ++g) {
            const int m = m0 + wm * 64 + i * 16 + hk * 4 + g;
            if (m < cnt) {
                u16* dst = H + (size_t)(base + m) * HID + n0 + wn * 64 + lr;
                #pragma unroll
                for (int j = 0; j < 4; ++j)
                    dst[j * 16] = f2bf(fmaxf(acc[i][j][g] + bias[j], 0.f));
            }
        }
    }
}

// ---------------------------------------------------------------------------
// Grouped MFMA GEMM2: out += gate*(H @ W2t^T + b2).  (r6-validated, verbatim)
// ---------------------------------------------------------------------------
__global__ __launch_bounds__(256, 4) void k_ffn2(
    const u16* __restrict__ Hb,     // [NPAIR][4096]
    const u16* __restrict__ W2t,    // [E][1024][4096]
    const float* __restrict__ b2,
    const int* __restrict__ counts, const int* __restrict__ offsets,
    const int* __restrict__ list_tok, const float* __restrict__ list_gate,
    float* __restrict__ out)
{
    const int bid = blockIdx.x;
    const int n_t = bid & 7;
    const int wsl = bid >> 3;

    int e, m_t;
    if (!work_map(counts, wsl, e, m_t)) return;
    const int cnt  = counts[e];
    const int base = offsets[e];
    const int m0   = m_t * 128;
    const int n0   = n_t * 128;
    const u16* __restrict__ Be = W2t + (size_t)e * (D_MODEL * HID);

    __shared__ __align__(16) u16 SA[2 * 4096];
    __shared__ __align__(16) u16 SB[2 * 4096];
    __shared__ int   s_tok[128];
    __shared__ float s_gate[128];

    const int tid = threadIdx.x;
    if (tid < 128) {
        const int sl = base + min(m0 + tid, cnt - 1);
        s_tok[tid]  = list_tok[sl];
        s_gate[tid] = list_gate[sl];
    }
    __syncthreads();

    int ar0, ak0, ar1, ak1;
    chunk_map(tid, ar0, ak0);
    chunk_map(tid + 256, ar1, ak1);
    const u16* Asrc0 = Hb + (size_t)(base + min(m0 + ar0, cnt - 1)) * HID + ak0;
    const u16* Asrc1 = Hb + (size_t)(base + min(m0 + ar1, cnt - 1)) * HID + ak1;
    const u16* Bsrc0 = Be + (size_t)(n0 + ar0) * HID + ak0;
    const u16* Bsrc1 = Be + (size_t)(n0 + ar1) * HID + ak1;

    const int lane = tid & 63, lr = lane & 15, hk = lane >> 4;
    const int w = tid >> 6, wm = w >> 1, wn = w & 1;
    const int colb  = ((((lr & 1) << 2) + hk) ^ (lr >> 1)) << 4;
    const int baseA = ((wm * 32 + (lr >> 1)) << 7) + colb;
    const int baseB = ((wn * 32 + (lr >> 1)) << 7) + colb;

    float bias[4];
    #pragma unroll
    for (int j = 0; j < 4; ++j) bias[j] = b2[(size_t)e * D_MODEL + n0 + wn * 64 + j * 16 + lr];

    f32x4 acc[4][4] = {};

    auto STAGE = [&](int s, int t) {
        const int kt = t * 32;
        char* Ab = (char*)SA + s * 8192;
        char* Bb = (char*)SB + s * 8192;
        glds16(Asrc0 + kt, Ab + tid * 16);
        glds16(Asrc1 + kt, Ab + (tid + 256) * 16);
        glds16(Bsrc0 + kt, Bb + tid * 16);
        glds16(Bsrc1 + kt, Bb + (tid + 256) * 16);
    };
    auto COMPUTE = [&](int s) {
        const char* Ab = (const char*)SA + s * 8192;
        const char* Bb = (const char*)SB + s * 8192;
        bf16x8 a[4], b[4];
        #pragma unroll
        for (int i = 0; i < 4; ++i) a[i] = *(const bf16x8*)(Ab + baseA + i * 1024);
        #pragma unroll
        for (int j = 0; j < 4; ++j) b[j] = *(const bf16x8*)(Bb + baseB + j * 1024);
        #pragma unroll
        for (int i = 0; i < 4; ++i)
            #pragma unroll
            for (int j = 0; j < 4; ++j)
                acc[i][j] = __builtin_amdgcn_mfma_f32_16x16x32_bf16(a[i], b[j], acc[i][j], 0, 0, 0);
    };

    const int NT = HID / 32;                    // 128
    STAGE(0, 0);
    STAGE(1, 1);
    for (int t = 0; t < NT; ++t) {
        if (t < NT - 1) { asm volatile("s_waitcnt vmcnt(4)" ::: "memory"); }
        else            { asm volatile("s_waitcnt vmcnt(0)" ::: "memory"); }
        __builtin_amdgcn_s_barrier();
        __builtin_amdgcn_sched_barrier(0);
        COMPUTE(t & 1);
        __builtin_amdgcn_sched_barrier(0);
        __builtin_amdgcn_s_barrier();
        if (t + 2 < NT) STAGE(t & 1, t + 2);
    }

    #pragma unroll
    for (int i = 0; i < 4; ++i) {
        #pragma unroll
        for (int g = 0; g < 4; ++g) {
            const int m = m0 + wm * 64 + i * 16 + hk * 4 + g;
            if (m < cnt) {
                const int   mm = m - m0;
                const int   tk = s_tok[mm];
                const float gt = s_gate[mm];
                float* dst = out + (size_t)tk * D_MODEL + n0 + wn * 64 + lr;
                #pragma unroll
                for (int j = 0; j < 4; ++j)
                    unsafeAtomicAdd(dst + j * 16, gt * (acc[i][j][g] + bias[j]));
            }
        }
    }
}

// ---------------------------------------------------------------------------
extern "C" void kernel_launch(void* const* d_in, const int* in_sizes, int n_in,
                              void* d_out, int out_size, void* d_ws, size_t ws_size,
                              hipStream_t stream)
{
    const float* x     = (const float*)d_in[0];
    const float* noise = (const float*)d_in[1];
    const float* Wr    = (const float*)d_in[2];
    const float* br    = (const float*)d_in[3];
    const float* Wn    = (const float*)d_in[4];
    const float* bn    = (const float*)d_in[5];
    const float* W1    = (const float*)d_in[6];
    const float* b1    = (const float*)d_in[7];
    const float* W2    = (const float*)d_in[8];
    const float* b2    = (const float*)d_in[9];
    float* out = (float*)d_out;

    char* ws = (char*)d_ws;
    int*   counts    = (int*)(ws + WS_COUNTS);
    int*   cursor    = (int*)(ws + WS_CURSOR);
    int*   offsets   = (int*)(ws + WS_OFFSETS);
    int*   tok_e     = (int*)(ws + WS_TOKE);
    float* tok_g     = (float*)(ws + WS_TOKG);
    int*   list_tok  = (int*)(ws + WS_LTOK);
    float* list_gate = (float*)(ws + WS_LGATE);
    u16*   xb        = (u16*)(ws + WS_XB);
    u16*   W1b       = (u16*)(ws + WS_WB);
    u16*   Hb        = (u16*)(ws + WS_H);

    const bool big = (ws_size >= WS_NEEDED);
    u16* W2b = big ? (u16*)(ws + WS_W2) : W1b;

    hipMemsetAsync(ws, 0, 128, stream);
    hipMemsetAsync(d_out, 0, (size_t)out_size * sizeof(float), stream);

    // cvtW1 (2048 blocks) + router (4096 blocks) co-scheduled
    k_router_cvt<<<CVT1B + T_TOK, 256, 0, stream>>>(
        x, noise, Wr, br, Wn, bn, counts, tok_e, tok_g, xb, W1, W1b);
    k_prefix<<<1, 64, 0, stream>>>(counts, offsets);
    k_scatter<<<NPAIR / 256, 256, 0, stream>>>(tok_e, tok_g, offsets, cursor,
                                               list_tok, list_gate);

    if (big) {
        // ffn1 (2304 blocks) + cvtW2 (2048 blocks) co-scheduled
        k_ffn1m<<<FFN1B + CVT2B, 256, 0, stream>>>(
            xb, W1b, b1, counts, offsets, list_tok, Hb, W2, W2b);
    } else {
        k_ffn1m<<<FFN1B, 256, 0, stream>>>(
            xb, W1b, b1, counts, offsets, list_tok, Hb, W2, W2b);
        k_cvtT<<<dim3(D_MODEL / 128, HID / 128, N_EXP), 256, 0, stream>>>(
            W2, W2b, HID, D_MODEL);
    }

    k_ffn2<<<8 * WSLOTS, 256, 0, stream>>>(Hb, W2b, b2, counts, offsets,
                                           list_tok, list_gate, out);
}